// Round 13
// baseline (294.536 us; speedup 1.0000x reference)
//
#include <hip/hip_runtime.h>
#include <stdint.h>
#include <stddef.h>

// DIM=2048, H=16, Q_RANK=768, KV_RANK=512, QK_STATIC=128, QK_ROT=64,
// QK_TOTAL=192, V_DIM=128, BS=2, SEQ=1024, NTOK=2048.
// Score contraction absorbed on the K side: kh[b,h] = kvn @ W_k[h]^T (128-dim),
// so scores = [q_static | q_rot] . [kh | k_rot] over 192 dims (vs 576).

typedef __attribute__((ext_vector_type(8))) short bf16x8;
typedef __attribute__((ext_vector_type(4))) float f32x4;

__device__ inline float b2f(unsigned short v){
    union { unsigned u; float f; } x; x.u = ((unsigned)v) << 16; return x.f;
}
__device__ inline unsigned short f2b(float f){
    union { float f; unsigned u; } x; x.f = f;
    unsigned r = x.u + 0x7fffu + ((x.u >> 16) & 1u);
    return (unsigned short)(r >> 16);
}

// async global->LDS, 16B per lane. LDS dest = wave-uniform base + lane*16.
__device__ __forceinline__ void gl2lds16(const unsigned short* g, unsigned short* l){
    __builtin_amdgcn_global_load_lds(
        (__attribute__((address_space(1))) void*)const_cast<unsigned short*>(g),
        (__attribute__((address_space(3))) void*)l,
        16, 0, 0);
}

// Shared GEMM body: C[M,N](+=bias) = alpha*(A @ B^T), bf16 in, fp32 acc.
// 128x128 tile, BK=32, 4 waves 2x2, 16x16x32 MFMA, 3-deep global_load_lds
// pipeline (vmcnt(4) waits, raw s_barrier, no full drain). LDS bank swizzle:
// stage global chunk (lane&3)^((lane>>3)&3); reads use chunk g^((row>>1)&3).
// causal bit0: -1e9 above diagonal in epilogue.
template<typename TC>
static __device__ __forceinline__ void gemm_body(
    unsigned short (*As)[4096], unsigned short (*Bs)[4096],
    const unsigned short* A, const unsigned short* B,
    const float* bias, TC* C,
    int N, int K, int lda, int ldb, int ldc,
    int m0, int n0, float alpha, int causal)
{
    const int tid = threadIdx.x, w = tid >> 6, lane = tid & 63;
    const int wm = w >> 1, wn = w & 1;

    const int srow = w * 32 + (lane >> 2);
    const int schunk = ((lane & 3) ^ ((lane >> 3) & 3)) * 8;   // row-bit-1/2 swizzle
    const unsigned short* gA = A + (size_t)(m0 + srow) * lda + schunk;
    const unsigned short* gB = B + (size_t)(n0 + srow) * ldb + schunk;

    const int ktiles = K >> 5;
    auto stage = [&](int buf, int kt){
        const int k0 = kt << 5;
        gl2lds16(gA + k0,            &As[buf][w * 1024]);
        gl2lds16(gA + k0 + 16 * lda, &As[buf][w * 1024 + 512]);
        gl2lds16(gB + k0,            &Bs[buf][w * 1024]);
        gl2lds16(gB + k0 + 16 * ldb, &Bs[buf][w * 1024 + 512]);
    };
    stage(0, 0);
    if (ktiles > 1) stage(1, 1);

    f32x4 acc[4][4] = {};
    const int lm = lane & 15;
    const int kq = (((lane >> 4) ^ (lm >> 1)) & 3) * 8;        // matches stage swizzle

    int cur = 0;
    for (int kt = 0; kt < ktiles; ++kt){
        if (kt + 1 < ktiles) __builtin_amdgcn_s_waitcnt(0xF74);
        else                 __builtin_amdgcn_s_waitcnt(0xF70);
        __builtin_amdgcn_s_barrier();
        __asm__ volatile("" ::: "memory");
        if (kt + 2 < ktiles) stage(cur >= 1 ? cur - 1 : 2, kt + 2);
        bf16x8 af[4], bfr[4];
        #pragma unroll
        for (int i = 0; i < 4; ++i)
            af[i] = *(const bf16x8*)&As[cur][(wm * 64 + i * 16 + lm) * 32 + kq];
        #pragma unroll
        for (int j = 0; j < 4; ++j)
            bfr[j] = *(const bf16x8*)&Bs[cur][(wn * 64 + j * 16 + lm) * 32 + kq];
        #pragma unroll
        for (int i = 0; i < 4; ++i)
            #pragma unroll
            for (int j = 0; j < 4; ++j)
                acc[i][j] = __builtin_amdgcn_mfma_f32_16x16x32_bf16(af[i], bfr[j], acc[i][j], 0, 0, 0);
        __asm__ volatile("" ::: "memory");
        cur = (cur == 2) ? 0 : cur + 1;
    }

    // C/D layout: col = lane&15, row = (lane>>4)*4 + reg
    #pragma unroll
    for (int i = 0; i < 4; ++i){
        const int m = m0 + wm * 64 + i * 16 + (lane >> 4) * 4;
        #pragma unroll
        for (int j = 0; j < 4; ++j){
            const int n = n0 + wn * 64 + j * 16 + lm;
            if (n < N){
                const float bb = bias ? bias[n] : 0.f;
                #pragma unroll
                for (int r = 0; r < 4; ++r){
                    float v = acc[i][j][r] * alpha + bb;
                    if ((causal & 1) && n > m + r) v = -1e9f;
                    if constexpr (sizeof(TC) == 2)
                        C[(size_t)(m + r) * ldc + n] = (TC)f2b(v);
                    else
                        C[(size_t)(m + r) * ldc + n] = (TC)v;
                }
            }
        }
    }
}

// Generic launcher (R6-exact).
// causal bit0: compact triangular tile decode (index = bm), mask in epilogue.
// causal bit1: K = min(K, m0+128).  causal bit2: z-first grid.
template<typename TC>
__global__ __launch_bounds__(256) void mfma_gemm_bt(
    const unsigned short* __restrict__ A, const unsigned short* __restrict__ B,
    const float* __restrict__ bias, TC* __restrict__ C,
    int M, int N, int K, int lda, int ldb, int ldc,
    int zdiv, long sA_hi, long sA_lo, long sB_hi, long sB_lo, long sC_hi, long sC_lo,
    float alpha, int causal)
{
    int z, bm, bn;
    if (causal & 4){ z = blockIdx.x; bm = blockIdx.y; bn = blockIdx.z; }
    else           { z = blockIdx.z; bm = blockIdx.y; bn = blockIdx.x; }
    int m0, n0;
    if (causal & 1){
        int i = bm;
        int mt = (int)((sqrtf(8.f * i + 1.f) - 1.f) * 0.5f);
        while ((mt + 1) * (mt + 2) / 2 <= i) ++mt;
        while (mt * (mt + 1) / 2 > i) --mt;
        n0 = (i - mt * (mt + 1) / 2) * 128;
        m0 = mt * 128;
    } else { m0 = bm * 128; n0 = bn * 128; }
    if (causal & 2) K = min(K, m0 + 128);

    __shared__ unsigned short As[3][4096];
    __shared__ unsigned short Bs[3][4096];
    const int zh = z / zdiv, zl = z % zdiv;
    A += (size_t)zh * sA_hi + (size_t)zl * sA_lo;
    B += (size_t)zh * sB_hi + (size_t)zl * sB_lo;
    C += (size_t)zh * sC_hi + (size_t)zl * sC_lo;

    gemm_body<TC>(As, Bs, A, B, bias, C, N, K, lda, ldb, ldc, m0, n0, alpha, causal);
}

// Merged vhT + kh + k3 launch (896 blocks, 1-D). All three GEMMs depend only
// on fdp outputs (kcat, qn), so they can share one grid: the k3 blocks
// backfill the vk tail instead of launching into an empty GPU afterwards.
// id < 512  (vk part, EXACT old dispatch order: x=id&63, y=id>>6):
//   p=x&1, z=x>>1. p=0: vhT[b][h] = w_v[h] @ kvn[b]^T (M=128,N=1024)
//                  p=1: khcat[b,h] = kvn[b] @ w_k[h]^T (M=1024,N=128)
// id >= 512 (k3 part, EXACT old order: bn=lid%24 fastest, bm=lid/24):
//   qu = bf16(qn @ q_up_w^T + q_up_b)  (M=2048,N=3072,K=768)
__global__ __launch_bounds__(256) void mfma_gemm_vk3(
    const unsigned short* __restrict__ kvuw,  // [4096][512]: w_k rows 0..2047, w_v 2048..4095
    const unsigned short* __restrict__ kcat,  // [2048][576] (kvn rows, ldb=576)
    unsigned short* __restrict__ vhT,         // [2][16][128][1024]
    unsigned short* __restrict__ khcat,       // [32][1024][192]
    const unsigned short* __restrict__ qn,    // [2048][768]
    const unsigned short* __restrict__ quw,   // [3072][768]
    const float* __restrict__ q_up_b,
    unsigned short* __restrict__ qu)          // [2048][3072]
{
    __shared__ unsigned short As[3][4096];
    __shared__ unsigned short Bs[3][4096];
    const int id = blockIdx.x;
    if (id < 512){
        const int x = id & 63, y = id >> 6;
        const int p = x & 1, z = x >> 1;
        const int b = z >> 4, h = z & 15;
        if (p == 0){
            const unsigned short* A = kvuw + 1048576 + (size_t)h * 65536;  // w_v[h]
            const unsigned short* B = kcat + (size_t)b * 589824;
            unsigned short* C = vhT + (size_t)b * 2097152 + (size_t)h * 131072;
            gemm_body<unsigned short>(As, Bs, A, B, nullptr, C,
                                      1024, 512, 512, 576, 1024, 0, y * 128, 1.0f, 0);
        } else {
            const unsigned short* A = kcat + (size_t)b * 589824;
            const unsigned short* B = kvuw + (size_t)h * 65536;            // w_k[h]
            unsigned short* C = khcat + (size_t)b * 3145728 + (size_t)h * 196608;
            gemm_body<unsigned short>(As, Bs, A, B, nullptr, C,
                                      128, 512, 576, 512, 192, y * 128, 0, 1.0f, 0);
        }
    } else {
        const int lid = id - 512;             // 0..383
        const int bn = lid % 24, bm = lid / 24;
        gemm_body<unsigned short>(As, Bs, qn, quw, q_up_b, qu,
                                  3072, 768, 768, 768, 3072,
                                  bm * 128, bn * 128, 1.0f, 0);
    }
}

// Fused causal attention v12: v10 body (LPT queue + XCD-local z, measured
// best 41.4us) + in-kernel q-RoPE.
//
// q-RoPE absorbed here (rope_q_krot kernel deleted): each (tok,h) q_rot
// slice is consumed by exactly ONE flash block, and the Q chunk-2 fragment
// layout makes the RoPE pair lane-local: af[i][0][e] = col 128+g*8+e,
// af[i][1][e] = col 160+g*8+e — exactly the (d, d+32) pair. At the first
// c=2 phase (Q all LDS-resident: vmcnt(16) retired all 6 Q loads; barrier
// covers cross-wave), hoist the 4 chunk-2 fragments into registers, rope
// in f32 (same powf/cosf/sinf as the old kernel -> identical rounding),
// reuse registers for all later iterations. VGPR +16, one-time ~16 sincos.
__global__ __launch_bounds__(256) void flash_attn(
    const unsigned short* __restrict__ qu,    // [2048][3072], q_rot UN-roped
    const unsigned short* __restrict__ khcat, // [32][1024][192] = [kh | k_rot]
    const unsigned short* __restrict__ vhT,   // [2][16][128][1024]
    unsigned short* __restrict__ ctx)         // [2048][2048]
{
    const int t = blockIdx.x;
    const int cls = t >> 6;                   // 0..7, nkt = 8-cls (LPT order)
    const int idx = t & 63;
    const int z = (idx & 7) + 8 * ((idx >> 3) & 3);  // z%8 == t%8 -> XCD-local
    const int mt = 2 * (7 - cls) + (idx >> 5);
    const int b = z >> 4, h = z & 15;
    const int m0 = mt * 64;
    const int nkt = (mt >> 1) + 1;            // == 8-cls

    __shared__ char smem[74240];
    unsigned short (*Qs)[4096] = (unsigned short (*)[4096])smem;            // 3 x 64x64 (Q resident)
    unsigned short (*Ks)[8192] = (unsigned short (*)[8192])(smem + 24576);  // 3 x 128x64
    unsigned short* Ps = (unsigned short*)(smem + 24576);                   // 64x136, aliases Ks[0..1]
    float* lrow = (float*)(smem + 73728);                                   // [2][64]

    const unsigned short* kB = khcat + (size_t)z * 196608;
    const unsigned short* vB = vhT + (size_t)z * 131072;

    const int tid = threadIdx.x, w = tid >> 6, lane = tid & 63;
    const int wm = w >> 1, wn = w & 1;
    const int lm = lane & 15, g = lane >> 4;
    const int kq = g * 8;
    const int rs7 = lm & 7;                   // row&7 for swizzled reads

    if (tid < 128) lrow[tid] = 0.f;

    const int srow8 = lane >> 3;              // 0..7
    const int soff8 = ((lane & 7) ^ (lane >> 3)) * 8;  // swizzled global chunk
    const unsigned short* gQ = qu + (size_t)(b * 1024 + m0 + w * 16 + srow8) * 3072
                               + h * 192 + soff8;

    // Q resident: 192 k = 3 chunk-buffers, staged once (6 loads/wave).
    #pragma unroll
    for (int c = 0; c < 3; ++c){
        gl2lds16(gQ + c * 64,            &Qs[c][w * 1024]);
        gl2lds16(gQ + c * 64 + 8 * 3072, &Qs[c][w * 1024 + 512]);
    }

    // K chunks with FIXED buffer roles: chunk0 -> Ks[2] (prefetched one
    // kv-tile ahead), chunk1 -> Ks[0], chunk2 -> Ks[1].
    auto stageK = [&](int buf, int kt, int c){
        const unsigned short* gK = kB + (size_t)(kt * 128 + w * 32 + srow8) * 192
                                   + c * 64 + soff8;
        gl2lds16(gK,            &Ks[buf][w * 2048]);
        gl2lds16(gK + 8 * 192,  &Ks[buf][w * 2048 + 512]);
        gl2lds16(gK + 16 * 192, &Ks[buf][w * 2048 + 1024]);
        gl2lds16(gK + 24 * 192, &Ks[buf][w * 2048 + 1536]);
    };
    stageK(2, 0, 0);                          // chunk0 of tile 0

    f32x4 Oacc[2][4] = {};
    const float scl = 0.07216878364870322f;   // 1/sqrt(192)
    bf16x8 qrot[2][2];                        // roped Q chunk-2 fragments

    for (int kt = 0; kt < nkt; ++kt){
        stageK(0, kt, 1);                     // chunk1 -> buf0 (Ps dead now)
        stageK(1, kt, 2);                     // chunk2 -> buf1
        __asm__ volatile("" ::: "memory");    // pin V loads AFTER K stages
        bf16x8 vfr[4][4];
        #pragma unroll
        for (int j = 0; j < 4; ++j)
            #pragma unroll
            for (int kc = 0; kc < 4; ++kc)
                vfr[j][kc] = *(const bf16x8*)(vB + (size_t)(wn * 64 + j * 16 + lm) * 1024
                                              + kt * 128 + kc * 32 + kq);
        __asm__ volatile("" ::: "memory");

        // vm queue (oldest first), steady state: [pf chunk0(4)] (kt=0: Q(6)+
        // chunk0(4)), chunk1(4), chunk2(4), V(16) = 28 (34 on kt=0).
        f32x4 S[2][4] = {};
        #pragma unroll
        for (int c = 0; c < 3; ++c){
            if      (c == 0) __builtin_amdgcn_s_waitcnt(0x4F78);  // vmcnt(24): chunk0 (+Q) in
            else if (c == 1) __builtin_amdgcn_s_waitcnt(0x4F74);  // vmcnt(20): chunk1 in
            else             __builtin_amdgcn_s_waitcnt(0x4F70);  // vmcnt(16): chunk2 in, V in flight
            __builtin_amdgcn_s_barrier();
            __asm__ volatile("" ::: "memory");
            const int bufc = (c == 0) ? 2 : (c - 1);
            bf16x8 af[2][2], bfr[4][2];
            if (c < 2){
                #pragma unroll
                for (int i = 0; i < 2; ++i)
                    #pragma unroll
                    for (int kk = 0; kk < 2; ++kk)
                        af[i][kk] = *(const bf16x8*)&Qs[c][(wm * 32 + i * 16 + lm) * 64
                                                           + (((kk * 4 + g) ^ rs7) * 8)];
            } else {
                if (kt == 0){
                    // one-time: read chunk-2 fragments + rope in f32
                    #pragma unroll
                    for (int i = 0; i < 2; ++i)
                        #pragma unroll
                        for (int kk = 0; kk < 2; ++kk)
                            qrot[i][kk] = *(const bf16x8*)&Qs[2][(wm * 32 + i * 16 + lm) * 64
                                                                 + (((kk * 4 + g) ^ rs7) * 8)];
                    #pragma unroll
                    for (int i = 0; i < 2; ++i){
                        const float si = (float)(m0 + wm * 32 + i * 16 + lm);
                        #pragma unroll
                        for (int e = 0; e < 8; ++e){
                            const int d = g * 8 + e;
                            const float ang = si * powf(10000.f, -(float)d / 32.f);
                            const float cs = cosf(ang), sn = sinf(ang);
                            const float x1 = b2f((unsigned short)qrot[i][0][e]);
                            const float x2 = b2f((unsigned short)qrot[i][1][e]);
                            qrot[i][0][e] = (short)f2b(x1 * cs - x2 * sn);
                            qrot[i][1][e] = (short)f2b(x2 * cs + x1 * sn);
                        }
                    }
                }
                #pragma unroll
                for (int i = 0; i < 2; ++i)
                    #pragma unroll
                    for (int kk = 0; kk < 2; ++kk)
                        af[i][kk] = qrot[i][kk];
            }
            #pragma unroll
            for (int j = 0; j < 4; ++j)
                #pragma unroll
                for (int kk = 0; kk < 2; ++kk)
                    bfr[j][kk] = *(const bf16x8*)&Ks[bufc][(wn * 64 + j * 16 + lm) * 64
                                                           + (((kk * 4 + g) ^ rs7) * 8)];
            __builtin_amdgcn_s_setprio(1);
            #pragma unroll
            for (int kk = 0; kk < 2; ++kk)
                #pragma unroll
                for (int i = 0; i < 2; ++i)
                    #pragma unroll
                    for (int j = 0; j < 4; ++j)
                        S[i][j] = __builtin_amdgcn_mfma_f32_16x16x32_bf16(af[i][kk], bfr[j][kk], S[i][j], 0, 0, 0);
            __builtin_amdgcn_s_setprio(0);
            __asm__ volatile("" ::: "memory");
        }
        // all QK reads of Ks done -> Ps (alias) writable. lgkm-only barrier:
        // keep the vm queue (V + upcoming prefetch) alive across it.
        __builtin_amdgcn_s_waitcnt(0xC07F);   // lgkmcnt(0), vmcnt untouched
        __builtin_amdgcn_s_barrier();
        __asm__ volatile("" ::: "memory");
        if (kt + 1 < nkt) stageK(2, kt + 1, 0);   // prefetch next chunk0 -> buf2

        // softmax numerator (global-index causal mask on the diagonal tile);
        // row sums; P -> LDS (aliased on Ks[0..1]) in [m][k] layout.
        const bool diag = (kt == (mt >> 1));
        #pragma unroll
        for (int i = 0; i < 2; ++i){
            float rs[4] = {0.f, 0.f, 0.f, 0.f};
            #pragma unroll
            for (int j = 0; j < 4; ++j){
                const int nloc = wn * 64 + j * 16 + lm;
                #pragma unroll
                for (int r2 = 0; r2 < 4; ++r2){
                    const int mloc = wm * 32 + i * 16 + g * 4 + r2;
                    float p = __expf(S[i][j][r2] * scl);
                    if (diag && (kt * 128 + nloc) > (m0 + mloc)) p = 0.f;
                    rs[r2] += p;
                    Ps[mloc * 136 + nloc] = f2b(p);
                }
            }
            #pragma unroll
            for (int r2 = 0; r2 < 4; ++r2){
                rs[r2] += __shfl_xor(rs[r2], 1, 64);
                rs[r2] += __shfl_xor(rs[r2], 2, 64);
                rs[r2] += __shfl_xor(rs[r2], 4, 64);
                rs[r2] += __shfl_xor(rs[r2], 8, 64);
            }
            if (lm == 0){
                #pragma unroll
                for (int r2 = 0; r2 < 4; ++r2)
                    lrow[wn * 64 + wm * 32 + i * 16 + g * 4 + r2] += rs[r2];
            }
        }
        __asm__ volatile("" ::: "memory");
        __builtin_amdgcn_s_waitcnt(0xC07F);   // Ps + lrow visible
        __builtin_amdgcn_s_barrier();
        __asm__ volatile("" ::: "memory");

        // O += P @ V^T  (A = Ps rows, B = vfr registers). V drained here
        // (in-order vm retirement; prefetched chunk0 may stay in flight).
        if (kt + 1 < nkt) __builtin_amdgcn_s_waitcnt(0xF74);  // vmcnt(4)
        else              __builtin_amdgcn_s_waitcnt(0xF70);  // vmcnt(0)
        #pragma unroll
        for (int kc = 0; kc < 4; ++kc){
            bf16x8 pa[2];
            #pragma unroll
            for (int i = 0; i < 2; ++i)
                pa[i] = *(const bf16x8*)&Ps[(wm * 32 + i * 16 + lm) * 136 + kc * 32 + kq];
            __builtin_amdgcn_s_setprio(1);
            #pragma unroll
            for (int i = 0; i < 2; ++i)
                #pragma unroll
                for (int j = 0; j < 4; ++j)
                    Oacc[i][j] = __builtin_amdgcn_mfma_f32_16x16x32_bf16(pa[i], vfr[j][kc], Oacc[i][j], 0, 0, 0);
            __builtin_amdgcn_s_setprio(0);
        }
        __asm__ volatile("" ::: "memory");
        __builtin_amdgcn_s_waitcnt(0xC07F);   // Ps reads done -> next kt restages buf0/1
        __builtin_amdgcn_s_barrier();
        __asm__ volatile("" ::: "memory");
    }

    // normalize and store: ctx[(b*1024+m0+row)][h*128 + col]
    unsigned short* cBase = ctx + ((size_t)(b * 1024 + m0)) * 2048 + h * 128;
    #pragma unroll
    for (int i = 0; i < 2; ++i){
        #pragma unroll
        for (int r2 = 0; r2 < 4; ++r2){
            const int row = wm * 32 + i * 16 + g * 4 + r2;
            const float inv = 1.f / (lrow[row] + lrow[64 + row]);
            #pragma unroll
            for (int j = 0; j < 4; ++j){
                const int col = wn * 64 + j * 16 + lm;
                cBase[(size_t)row * 2048 + col] = f2b(Oacc[i][j][r2] * inv);
            }
        }
    }
}

// One launch casting all six f32 weight/activation blobs to bf16.
__global__ __launch_bounds__(256) void cast_all(
    const float* __restrict__ s0, unsigned short* __restrict__ d0,   // x      4194304
    const float* __restrict__ s1, unsigned short* __restrict__ d1,   // q_down 1572864
    const float* __restrict__ s2, unsigned short* __restrict__ d2,   // q_up   2359296
    const float* __restrict__ s3, unsigned short* __restrict__ d3,   // kv_down1179648
    const float* __restrict__ s4, unsigned short* __restrict__ d4,   // kv_up  2097152
    const float* __restrict__ s5, unsigned short* __restrict__ d5)   // out_w  4194304
{
    long i = (long)(blockIdx.x * 256 + threadIdx.x) * 4;
    const float* s; unsigned short* d; long off;
    if      (i <  4194304L){ s = s0; d = d0; off = i; }
    else if (i <  5767168L){ s = s1; d = d1; off = i -  4194304L; }
    else if (i <  8126464L){ s = s2; d = d2; off = i -  5767168L; }
    else if (i <  9306112L){ s = s3; d = d3; off = i -  8126464L; }
    else if (i < 11403264L){ s = s4; d = d4; off = i -  9306112L; }
    else                   { s = s5; d = d5; off = i - 11403264L; }
    float4 v = *(const float4*)(s + off);
    *(ushort4*)(d + off) = make_ushort4(f2b(v.x), f2b(v.y), f2b(v.z), f2b(v.w));
}

// Fused down-proj epilogue. p = [4][2048][1344] bf16 split-K partials.
// Also broadcasts the roped k_rot into khcat cols 128..192 for all 16 heads
// (value already in a register; khcat cols 0..127 are written later by vk3 —
// disjoint bytes, no race).
__global__ __launch_bounds__(256) void fused_down_post(
    const unsigned short* __restrict__ p,
    const float* __restrict__ q_down_b, const float* __restrict__ kv_down_b,
    const float* __restrict__ q_norm_s, const float* __restrict__ kv_norm_s,
    unsigned short* __restrict__ qn, unsigned short* __restrict__ kcat,
    unsigned short* __restrict__ khcat)       // [32][1024][192]
{
    __shared__ float row[1344];
    __shared__ float red[4];
    const int t = blockIdx.x, tid = threadIdx.x;
    const long S = 2752512L; // 2048*1344
    const unsigned short* b0 = p + (size_t)t * 1344;
    for (int c = tid; c < 1344; c += 256){
        float v = b2f(b0[c]) + b2f(b0[c + S]) + b2f(b0[c + 2*S]) + b2f(b0[c + 3*S]);
        v += (c < 768) ? q_down_b[c] : kv_down_b[c - 768];
        row[c] = v;
    }
    __syncthreads();
    const int lane = tid & 63, w = tid >> 6;
    float ss = 0.f;
    for (int c = tid; c < 768; c += 256){ float v = row[c]; ss += v * v; }
    #pragma unroll
    for (int o = 32; o > 0; o >>= 1) ss += __shfl_xor(ss, o, 64);
    if (lane == 0) red[w] = ss;
    __syncthreads();
    const float inv1 = rsqrtf((red[0]+red[1]+red[2]+red[3]) / 768.f + 1e-6f);
    __syncthreads();
    ss = 0.f;
    for (int c = tid; c < 512; c += 256){ float v = row[768 + c]; ss += v * v; }
    #pragma unroll
    for (int o = 32; o > 0; o >>= 1) ss += __shfl_xor(ss, o, 64);
    if (lane == 0) red[w] = ss;
    __syncthreads();
    const float inv2 = rsqrtf((red[0]+red[1]+red[2]+red[3]) / 512.f + 1e-6f);
    for (int c = tid; c < 768; c += 256)
        qn[(size_t)t * 768 + c] = f2b(q_norm_s[c] * row[c] * inv1);
    for (int c = tid; c < 512; c += 256)
        kcat[(size_t)t * 576 + c] = f2b(kv_norm_s[c] * row[768 + c] * inv2);
    if (tid < 64){
        const int d = tid, s = t & 1023;
        float x  = row[1280 + d];
        float xp = (d < 32) ? -row[1280 + d + 32] : row[1280 + d - 32];
        float ang = (float)s * powf(10000.f, -(float)(2 * (d & 31)) / 64.f);
        const unsigned short kv = f2b(x * cosf(ang) + xp * sinf(ang));
        kcat[(size_t)t * 576 + 512 + d] = kv;
        // broadcast to khcat[b, 0..15][s][128+d]
        const size_t base = ((size_t)((t >> 10) * 16) * 1024 + s) * 192 + 128 + d;
        #pragma unroll
        for (int hh = 0; hh < 16; ++hh)
            khcat[base + (size_t)hh * 196608] = kv;
    }
}

// out = p[0] + p[1] + bias (p bf16 partials, out f32 2048x2048)
__global__ __launch_bounds__(256) void reduce_out(
    const unsigned short* __restrict__ p, const float* __restrict__ bias,
    float* __restrict__ out)
{
    const long S = 4194304L;
    long i = (long)(blockIdx.x * 256 + threadIdx.x) * 4;
    ushort4 a = *(const ushort4*)(p + i);
    ushort4 b = *(const ushort4*)(p + i + S);
    float4 bb = *(const float4*)(bias + (i & 2047));
    float4 r = make_float4(b2f(a.x) + b2f(b.x) + bb.x, b2f(a.y) + b2f(b.y) + bb.y,
                           b2f(a.z) + b2f(b.z) + bb.z, b2f(a.w) + b2f(b.w) + bb.w);
    *(float4*)(out + i) = r;
}

extern "C" void kernel_launch(void* const* d_in, const int* in_sizes, int n_in,
                              void* d_out, int out_size, void* d_ws, size_t ws_size,
                              hipStream_t stream)
{
    const float* x         = (const float*)d_in[0];
    const float* q_down_w  = (const float*)d_in[3];
    const float* q_down_b  = (const float*)d_in[4];
    const float* q_norm_s  = (const float*)d_in[5];
    const float* q_up_w    = (const float*)d_in[6];
    const float* q_up_b    = (const float*)d_in[7];
    const float* kv_down_w = (const float*)d_in[8];
    const float* kv_down_b = (const float*)d_in[9];
    const float* kv_norm_s = (const float*)d_in[10];
    const float* kv_up_w   = (const float*)d_in[11];
    const float* out_w     = (const float*)d_in[12];
    const float* out_b     = (const float*)d_in[13];
    float* out = (float*)d_out;

    // Workspace layout (bytes), peak 100,925,440:
    char* ws = (char*)d_ws;
    unsigned short* kvuw  = (unsigned short*)(ws + 0);           // [4096][512] (w_k rows 0..2047, w_v 2048..4095)
    unsigned short* outw  = (unsigned short*)(ws + 4194304);     // [2048][2048]
    unsigned short* kcat  = (unsigned short*)(ws + 12582912);    // [2048][576]
    unsigned short* vhT   = (unsigned short*)(ws + 14942208);    // [2][16][128][1024]
    unsigned short* khcat = (unsigned short*)(ws + 23330816);    // [32][1024][192]
    unsigned short* ctx   = (unsigned short*)(ws + 35913728);    // [2048][2048] bf16
    unsigned short* qu    = (unsigned short*)(ws + 44302336);    // [2048][3072] (live through flash)
    unsigned short* qn    = (unsigned short*)(ws + 56885248);    // [2048][768]
    unsigned short* p_qkv = (unsigned short*)(ws + 60030976);    // [4][2048][1344] bf16 (dead after fdp)
    unsigned short* p_out = (unsigned short*)(ws + 60030976);    // [2][2048][2048] bf16 (alias p_qkv)
    unsigned short* xb    = (unsigned short*)(ws + 82051072);    // [2048][2048]
    unsigned short* qkdw  = (unsigned short*)(ws + 90439680);    // [1408][2048] concat down-proj w
    unsigned short* quw   = (unsigned short*)(ws + 96206848);    // [3072][768]

    dim3 blk(256);

    // casts: q_down -> qkdw rows 0..767, kv_down -> qkdw rows 768..1343
    cast_all<<<15232, blk, 0, stream>>>(x, xb, q_down_w, qkdw, q_up_w, quw,
                                        kv_down_w, qkdw + 1572864, kv_up_w, kvuw, out_w, outw);

    // k1 (split-K x4, bf16 partials): p_qkv[s] = x[:, s*512:] @ qkdw[:, s*512:]^T
    mfma_gemm_bt<unsigned short><<<dim3(11, 16, 4), blk, 0, stream>>>(
        xb, qkdw, nullptr, p_qkv, 2048, 1344, 512, 2048, 2048, 1344,
        4, 0L, 512L, 0L, 512L, 0L, 2752512L, 1.0f, 0);
    // fused: partial-sum + biases + q-rmsnorm -> qn, kv-rmsnorm/rope -> kcat,
    // + roped k_rot broadcast into khcat cols 128..192
    fused_down_post<<<2048, blk, 0, stream>>>(p_qkv, q_down_b, kv_down_b,
                                              q_norm_s, kv_norm_s, qn, kcat, khcat);
    // merged vhT + kh + k3 (896 blocks: k3 backfills the vk tail)
    mfma_gemm_vk3<<<dim3(896), blk, 0, stream>>>(kvuw, kcat, vhT, khcat,
                                                 qn, quw, q_up_b, qu);
    // fused attention v12: LPT queue + XCD-local z + in-kernel q-RoPE
    flash_attn<<<dim3(512), blk, 0, stream>>>(qu, khcat, vhT, ctx);
    // k11 (split-K x2, bf16 partials, 512 blocks): p_out[s] = ctx[:, s*1024:] @ outw[:, s*1024:]^T
    mfma_gemm_bt<unsigned short><<<dim3(16, 16, 2), blk, 0, stream>>>(
        ctx, outw, nullptr, p_out, 2048, 2048, 1024, 2048, 2048, 2048,
        2, 0L, 1024L, 0L, 1024L, 0L, 4194304L, 1.0f, 0);
    // out = p_out[0] + p_out[1] + out_b
    reduce_out<<<4096, blk, 0, stream>>>(p_out, out_b, out);
}

// Round 14
// 284.327 us; speedup vs baseline: 1.0359x; 1.0359x over previous
//
#include <hip/hip_runtime.h>
#include <stdint.h>
#include <stddef.h>

// DIM=2048, H=16, Q_RANK=768, KV_RANK=512, QK_STATIC=128, QK_ROT=64,
// QK_TOTAL=192, V_DIM=128, BS=2, SEQ=1024, NTOK=2048.
// Score contraction absorbed on the K side: kh[b,h] = kvn @ W_k[h]^T (128-dim),
// so scores = [q_static | q_rot] . [kh | k_rot] over 192 dims (vs 576).

typedef __attribute__((ext_vector_type(8))) short bf16x8;
typedef __attribute__((ext_vector_type(4))) float f32x4;

__device__ inline float b2f(unsigned short v){
    union { unsigned u; float f; } x; x.u = ((unsigned)v) << 16; return x.f;
}
__device__ inline unsigned short f2b(float f){
    union { float f; unsigned u; } x; x.f = f;
    unsigned r = x.u + 0x7fffu + ((x.u >> 16) & 1u);
    return (unsigned short)(r >> 16);
}

// async global->LDS, 16B per lane. LDS dest = wave-uniform base + lane*16.
__device__ __forceinline__ void gl2lds16(const unsigned short* g, unsigned short* l){
    __builtin_amdgcn_global_load_lds(
        (__attribute__((address_space(1))) void*)const_cast<unsigned short*>(g),
        (__attribute__((address_space(3))) void*)l,
        16, 0, 0);
}

// Shared GEMM body: C[M,N](+=bias) = alpha*(A @ B^T), bf16 in, fp32 acc.
// 128x128 tile, BK=32, 4 waves 2x2, 16x16x32 MFMA, 3-deep global_load_lds
// pipeline (vmcnt(4) waits, raw s_barrier, no full drain). LDS bank swizzle:
// stage global chunk (lane&3)^((lane>>3)&3); reads use chunk g^((row>>1)&3).
// causal bit0: -1e9 above diagonal in epilogue.
template<typename TC>
static __device__ __forceinline__ void gemm_body(
    unsigned short (*As)[4096], unsigned short (*Bs)[4096],
    const unsigned short* A, const unsigned short* B,
    const float* bias, TC* C,
    int N, int K, int lda, int ldb, int ldc,
    int m0, int n0, float alpha, int causal)
{
    const int tid = threadIdx.x, w = tid >> 6, lane = tid & 63;
    const int wm = w >> 1, wn = w & 1;

    const int srow = w * 32 + (lane >> 2);
    const int schunk = ((lane & 3) ^ ((lane >> 3) & 3)) * 8;   // row-bit-1/2 swizzle
    const unsigned short* gA = A + (size_t)(m0 + srow) * lda + schunk;
    const unsigned short* gB = B + (size_t)(n0 + srow) * ldb + schunk;

    const int ktiles = K >> 5;
    auto stage = [&](int buf, int kt){
        const int k0 = kt << 5;
        gl2lds16(gA + k0,            &As[buf][w * 1024]);
        gl2lds16(gA + k0 + 16 * lda, &As[buf][w * 1024 + 512]);
        gl2lds16(gB + k0,            &Bs[buf][w * 1024]);
        gl2lds16(gB + k0 + 16 * ldb, &Bs[buf][w * 1024 + 512]);
    };
    stage(0, 0);
    if (ktiles > 1) stage(1, 1);

    f32x4 acc[4][4] = {};
    const int lm = lane & 15;
    const int kq = (((lane >> 4) ^ (lm >> 1)) & 3) * 8;        // matches stage swizzle

    int cur = 0;
    for (int kt = 0; kt < ktiles; ++kt){
        if (kt + 1 < ktiles) __builtin_amdgcn_s_waitcnt(0xF74);
        else                 __builtin_amdgcn_s_waitcnt(0xF70);
        __builtin_amdgcn_s_barrier();
        __asm__ volatile("" ::: "memory");
        if (kt + 2 < ktiles) stage(cur >= 1 ? cur - 1 : 2, kt + 2);
        bf16x8 af[4], bfr[4];
        #pragma unroll
        for (int i = 0; i < 4; ++i)
            af[i] = *(const bf16x8*)&As[cur][(wm * 64 + i * 16 + lm) * 32 + kq];
        #pragma unroll
        for (int j = 0; j < 4; ++j)
            bfr[j] = *(const bf16x8*)&Bs[cur][(wn * 64 + j * 16 + lm) * 32 + kq];
        #pragma unroll
        for (int i = 0; i < 4; ++i)
            #pragma unroll
            for (int j = 0; j < 4; ++j)
                acc[i][j] = __builtin_amdgcn_mfma_f32_16x16x32_bf16(af[i], bfr[j], acc[i][j], 0, 0, 0);
        __asm__ volatile("" ::: "memory");
        cur = (cur == 2) ? 0 : cur + 1;
    }

    // C/D layout: col = lane&15, row = (lane>>4)*4 + reg
    #pragma unroll
    for (int i = 0; i < 4; ++i){
        const int m = m0 + wm * 64 + i * 16 + (lane >> 4) * 4;
        #pragma unroll
        for (int j = 0; j < 4; ++j){
            const int n = n0 + wn * 64 + j * 16 + lm;
            if (n < N){
                const float bb = bias ? bias[n] : 0.f;
                #pragma unroll
                for (int r = 0; r < 4; ++r){
                    float v = acc[i][j][r] * alpha + bb;
                    if ((causal & 1) && n > m + r) v = -1e9f;
                    if constexpr (sizeof(TC) == 2)
                        C[(size_t)(m + r) * ldc + n] = (TC)f2b(v);
                    else
                        C[(size_t)(m + r) * ldc + n] = (TC)v;
                }
            }
        }
    }
}

// Generic launcher (R6-exact).
// causal bit0: compact triangular tile decode (index = bm), mask in epilogue.
// causal bit1: K = min(K, m0+128).  causal bit2: z-first grid.
template<typename TC>
__global__ __launch_bounds__(256) void mfma_gemm_bt(
    const unsigned short* __restrict__ A, const unsigned short* __restrict__ B,
    const float* __restrict__ bias, TC* __restrict__ C,
    int M, int N, int K, int lda, int ldb, int ldc,
    int zdiv, long sA_hi, long sA_lo, long sB_hi, long sB_lo, long sC_hi, long sC_lo,
    float alpha, int causal)
{
    int z, bm, bn;
    if (causal & 4){ z = blockIdx.x; bm = blockIdx.y; bn = blockIdx.z; }
    else           { z = blockIdx.z; bm = blockIdx.y; bn = blockIdx.x; }
    int m0, n0;
    if (causal & 1){
        int i = bm;
        int mt = (int)((sqrtf(8.f * i + 1.f) - 1.f) * 0.5f);
        while ((mt + 1) * (mt + 2) / 2 <= i) ++mt;
        while (mt * (mt + 1) / 2 > i) --mt;
        n0 = (i - mt * (mt + 1) / 2) * 128;
        m0 = mt * 128;
    } else { m0 = bm * 128; n0 = bn * 128; }
    if (causal & 2) K = min(K, m0 + 128);

    __shared__ unsigned short As[3][4096];
    __shared__ unsigned short Bs[3][4096];
    const int zh = z / zdiv, zl = z % zdiv;
    A += (size_t)zh * sA_hi + (size_t)zl * sA_lo;
    B += (size_t)zh * sB_hi + (size_t)zl * sB_lo;
    C += (size_t)zh * sC_hi + (size_t)zl * sC_lo;

    gemm_body<TC>(As, Bs, A, B, bias, C, N, K, lda, ldb, ldc, m0, n0, alpha, causal);
}

// Merged vhT + kh + k3 launch (896 blocks, 1-D). All three GEMMs depend only
// on fdp outputs (kcat, qn), so they can share one grid: the k3 blocks
// backfill the vk tail instead of launching into an empty GPU afterwards.
// id < 512  (vk part, EXACT old dispatch order: x=id&63, y=id>>6):
//   p=x&1, z=x>>1. p=0: vhT[b][h] = w_v[h] @ kvn[b]^T (M=128,N=1024)
//                  p=1: khcat[b,h] = kvn[b] @ w_k[h]^T (M=1024,N=128)
// id >= 512 (k3 part, EXACT old order: bn=lid%24 fastest, bm=lid/24):
//   qu = bf16(qn @ q_up_w^T + q_up_b)  (M=2048,N=3072,K=768)
__global__ __launch_bounds__(256) void mfma_gemm_vk3(
    const unsigned short* __restrict__ kvuw,  // [4096][512]: w_k rows 0..2047, w_v 2048..4095
    const unsigned short* __restrict__ kcat,  // [2048][576] (kvn rows, ldb=576)
    unsigned short* __restrict__ vhT,         // [2][16][128][1024]
    unsigned short* __restrict__ khcat,       // [32][1024][192]
    const unsigned short* __restrict__ qn,    // [2048][768]
    const unsigned short* __restrict__ quw,   // [3072][768]
    const float* __restrict__ q_up_b,
    unsigned short* __restrict__ qu)          // [2048][3072]
{
    __shared__ unsigned short As[3][4096];
    __shared__ unsigned short Bs[3][4096];
    const int id = blockIdx.x;
    if (id < 512){
        const int x = id & 63, y = id >> 6;
        const int p = x & 1, z = x >> 1;
        const int b = z >> 4, h = z & 15;
        if (p == 0){
            const unsigned short* A = kvuw + 1048576 + (size_t)h * 65536;  // w_v[h]
            const unsigned short* B = kcat + (size_t)b * 589824;
            unsigned short* C = vhT + (size_t)b * 2097152 + (size_t)h * 131072;
            gemm_body<unsigned short>(As, Bs, A, B, nullptr, C,
                                      1024, 512, 512, 576, 1024, 0, y * 128, 1.0f, 0);
        } else {
            const unsigned short* A = kcat + (size_t)b * 589824;
            const unsigned short* B = kvuw + (size_t)h * 65536;            // w_k[h]
            unsigned short* C = khcat + (size_t)b * 3145728 + (size_t)h * 196608;
            gemm_body<unsigned short>(As, Bs, A, B, nullptr, C,
                                      128, 512, 576, 512, 192, y * 128, 0, 1.0f, 0);
        }
    } else {
        const int lid = id - 512;             // 0..383
        const int bn = lid % 24, bm = lid / 24;
        gemm_body<unsigned short>(As, Bs, qn, quw, q_up_b, qu,
                                  3072, 768, 768, 768, 3072,
                                  bm * 128, bn * 128, 1.0f, 0);
    }
}

// Fused causal attention v10 (R12-exact; measured best 41.4us): v6 body +
// LPT (longest-first) global queue with XCD-local z.
//
// Makespan-limited under ~1 block/CU with greedy in-order backfill. LPT: 8
// classes of 64 blocks, class c has nkt=8-c (descending); greedy backfill
// pairs every CU to a total of EXACTLY 9 iters. Within a class,
// z=(idx&7)+8*((idx>>3)&3) keeps z%8==t%8 -> same-XCD K/V (FETCH 16.5MB).
// R13's in-kernel q-RoPE falsified (VALUBusy 19->37%, +20us): trig belongs
// in high-occupancy elementwise kernels, not the latency-bound flash body.
// Chunk0 cross-tile prefetch (Ks[2]); counted vmcnt (24/20/16); lgkm-only
// barriers; V drained at PV; s_setprio around MFMA clusters.
__global__ __launch_bounds__(256) void flash_attn(
    const unsigned short* __restrict__ qu,    // [2048][3072], q_rot slices roped
    const unsigned short* __restrict__ khcat, // [32][1024][192] = [kh | k_rot]
    const unsigned short* __restrict__ vhT,   // [2][16][128][1024]
    unsigned short* __restrict__ ctx)         // [2048][2048]
{
    const int t = blockIdx.x;
    const int cls = t >> 6;                   // 0..7, nkt = 8-cls (LPT order)
    const int idx = t & 63;
    const int z = (idx & 7) + 8 * ((idx >> 3) & 3);  // z%8 == t%8 -> XCD-local
    const int mt = 2 * (7 - cls) + (idx >> 5);
    const int b = z >> 4, h = z & 15;
    const int m0 = mt * 64;
    const int nkt = (mt >> 1) + 1;            // == 8-cls

    __shared__ char smem[74240];
    unsigned short (*Qs)[4096] = (unsigned short (*)[4096])smem;            // 3 x 64x64 (Q resident)
    unsigned short (*Ks)[8192] = (unsigned short (*)[8192])(smem + 24576);  // 3 x 128x64
    unsigned short* Ps = (unsigned short*)(smem + 24576);                   // 64x136, aliases Ks[0..1]
    float* lrow = (float*)(smem + 73728);                                   // [2][64]

    const unsigned short* kB = khcat + (size_t)z * 196608;
    const unsigned short* vB = vhT + (size_t)z * 131072;

    const int tid = threadIdx.x, w = tid >> 6, lane = tid & 63;
    const int wm = w >> 1, wn = w & 1;
    const int lm = lane & 15, g = lane >> 4;
    const int kq = g * 8;
    const int rs7 = lm & 7;                   // row&7 for swizzled reads

    if (tid < 128) lrow[tid] = 0.f;

    const int srow8 = lane >> 3;              // 0..7
    const int soff8 = ((lane & 7) ^ (lane >> 3)) * 8;  // swizzled global chunk
    const unsigned short* gQ = qu + (size_t)(b * 1024 + m0 + w * 16 + srow8) * 3072
                               + h * 192 + soff8;

    // Q resident: 192 k = 3 chunk-buffers, staged once (6 loads/wave).
    #pragma unroll
    for (int c = 0; c < 3; ++c){
        gl2lds16(gQ + c * 64,            &Qs[c][w * 1024]);
        gl2lds16(gQ + c * 64 + 8 * 3072, &Qs[c][w * 1024 + 512]);
    }

    // K chunks with FIXED buffer roles: chunk0 -> Ks[2] (prefetched one
    // kv-tile ahead), chunk1 -> Ks[0], chunk2 -> Ks[1].
    auto stageK = [&](int buf, int kt, int c){
        const unsigned short* gK = kB + (size_t)(kt * 128 + w * 32 + srow8) * 192
                                   + c * 64 + soff8;
        gl2lds16(gK,            &Ks[buf][w * 2048]);
        gl2lds16(gK + 8 * 192,  &Ks[buf][w * 2048 + 512]);
        gl2lds16(gK + 16 * 192, &Ks[buf][w * 2048 + 1024]);
        gl2lds16(gK + 24 * 192, &Ks[buf][w * 2048 + 1536]);
    };
    stageK(2, 0, 0);                          // chunk0 of tile 0

    f32x4 Oacc[2][4] = {};
    const float scl = 0.07216878364870322f;   // 1/sqrt(192)

    for (int kt = 0; kt < nkt; ++kt){
        stageK(0, kt, 1);                     // chunk1 -> buf0 (Ps dead now)
        stageK(1, kt, 2);                     // chunk2 -> buf1
        __asm__ volatile("" ::: "memory");    // pin V loads AFTER K stages
        bf16x8 vfr[4][4];
        #pragma unroll
        for (int j = 0; j < 4; ++j)
            #pragma unroll
            for (int kc = 0; kc < 4; ++kc)
                vfr[j][kc] = *(const bf16x8*)(vB + (size_t)(wn * 64 + j * 16 + lm) * 1024
                                              + kt * 128 + kc * 32 + kq);
        __asm__ volatile("" ::: "memory");

        // vm queue (oldest first), steady state: [pf chunk0(4)] (kt=0: Q(6)+
        // chunk0(4)), chunk1(4), chunk2(4), V(16) = 28 (34 on kt=0).
        f32x4 S[2][4] = {};
        #pragma unroll
        for (int c = 0; c < 3; ++c){
            if      (c == 0) __builtin_amdgcn_s_waitcnt(0x4F78);  // vmcnt(24): chunk0 (+Q) in
            else if (c == 1) __builtin_amdgcn_s_waitcnt(0x4F74);  // vmcnt(20): chunk1 in
            else             __builtin_amdgcn_s_waitcnt(0x4F70);  // vmcnt(16): chunk2 in, V in flight
            __builtin_amdgcn_s_barrier();
            __asm__ volatile("" ::: "memory");
            const int bufc = (c == 0) ? 2 : (c - 1);
            bf16x8 af[2][2], bfr[4][2];
            #pragma unroll
            for (int i = 0; i < 2; ++i)
                #pragma unroll
                for (int kk = 0; kk < 2; ++kk)
                    af[i][kk] = *(const bf16x8*)&Qs[c][(wm * 32 + i * 16 + lm) * 64
                                                       + (((kk * 4 + g) ^ rs7) * 8)];
            #pragma unroll
            for (int j = 0; j < 4; ++j)
                #pragma unroll
                for (int kk = 0; kk < 2; ++kk)
                    bfr[j][kk] = *(const bf16x8*)&Ks[bufc][(wn * 64 + j * 16 + lm) * 64
                                                           + (((kk * 4 + g) ^ rs7) * 8)];
            __builtin_amdgcn_s_setprio(1);
            #pragma unroll
            for (int kk = 0; kk < 2; ++kk)
                #pragma unroll
                for (int i = 0; i < 2; ++i)
                    #pragma unroll
                    for (int j = 0; j < 4; ++j)
                        S[i][j] = __builtin_amdgcn_mfma_f32_16x16x32_bf16(af[i][kk], bfr[j][kk], S[i][j], 0, 0, 0);
            __builtin_amdgcn_s_setprio(0);
            __asm__ volatile("" ::: "memory");
        }
        // all QK reads of Ks done -> Ps (alias) writable. lgkm-only barrier:
        // keep the vm queue (V + upcoming prefetch) alive across it.
        __builtin_amdgcn_s_waitcnt(0xC07F);   // lgkmcnt(0), vmcnt untouched
        __builtin_amdgcn_s_barrier();
        __asm__ volatile("" ::: "memory");
        if (kt + 1 < nkt) stageK(2, kt + 1, 0);   // prefetch next chunk0 -> buf2

        // softmax numerator (global-index causal mask on the diagonal tile);
        // row sums; P -> LDS (aliased on Ks[0..1]) in [m][k] layout.
        const bool diag = (kt == (mt >> 1));
        #pragma unroll
        for (int i = 0; i < 2; ++i){
            float rs[4] = {0.f, 0.f, 0.f, 0.f};
            #pragma unroll
            for (int j = 0; j < 4; ++j){
                const int nloc = wn * 64 + j * 16 + lm;
                #pragma unroll
                for (int r2 = 0; r2 < 4; ++r2){
                    const int mloc = wm * 32 + i * 16 + g * 4 + r2;
                    float p = __expf(S[i][j][r2] * scl);
                    if (diag && (kt * 128 + nloc) > (m0 + mloc)) p = 0.f;
                    rs[r2] += p;
                    Ps[mloc * 136 + nloc] = f2b(p);
                }
            }
            #pragma unroll
            for (int r2 = 0; r2 < 4; ++r2){
                rs[r2] += __shfl_xor(rs[r2], 1, 64);
                rs[r2] += __shfl_xor(rs[r2], 2, 64);
                rs[r2] += __shfl_xor(rs[r2], 4, 64);
                rs[r2] += __shfl_xor(rs[r2], 8, 64);
            }
            if (lm == 0){
                #pragma unroll
                for (int r2 = 0; r2 < 4; ++r2)
                    lrow[wn * 64 + wm * 32 + i * 16 + g * 4 + r2] += rs[r2];
            }
        }
        __asm__ volatile("" ::: "memory");
        __builtin_amdgcn_s_waitcnt(0xC07F);   // Ps + lrow visible
        __builtin_amdgcn_s_barrier();
        __asm__ volatile("" ::: "memory");

        // O += P @ V^T  (A = Ps rows, B = vfr registers). V drained here
        // (in-order vm retirement; prefetched chunk0 may stay in flight).
        if (kt + 1 < nkt) __builtin_amdgcn_s_waitcnt(0xF74);  // vmcnt(4)
        else              __builtin_amdgcn_s_waitcnt(0xF70);  // vmcnt(0)
        #pragma unroll
        for (int kc = 0; kc < 4; ++kc){
            bf16x8 pa[2];
            #pragma unroll
            for (int i = 0; i < 2; ++i)
                pa[i] = *(const bf16x8*)&Ps[(wm * 32 + i * 16 + lm) * 136 + kc * 32 + kq];
            __builtin_amdgcn_s_setprio(1);
            #pragma unroll
            for (int i = 0; i < 2; ++i)
                #pragma unroll
                for (int j = 0; j < 4; ++j)
                    Oacc[i][j] = __builtin_amdgcn_mfma_f32_16x16x32_bf16(pa[i], vfr[j][kc], Oacc[i][j], 0, 0, 0);
            __builtin_amdgcn_s_setprio(0);
        }
        __asm__ volatile("" ::: "memory");
        __builtin_amdgcn_s_waitcnt(0xC07F);   // Ps reads done -> next kt restages buf0/1
        __builtin_amdgcn_s_barrier();
        __asm__ volatile("" ::: "memory");
    }

    // normalize and store: ctx[(b*1024+m0+row)][h*128 + col]
    unsigned short* cBase = ctx + ((size_t)(b * 1024 + m0)) * 2048 + h * 128;
    #pragma unroll
    for (int i = 0; i < 2; ++i){
        #pragma unroll
        for (int r2 = 0; r2 < 4; ++r2){
            const int row = wm * 32 + i * 16 + g * 4 + r2;
            const float inv = 1.f / (lrow[row] + lrow[64 + row]);
            #pragma unroll
            for (int j = 0; j < 4; ++j){
                const int col = wn * 64 + j * 16 + lm;
                cBase[(size_t)row * 2048 + col] = f2b(Oacc[i][j][r2] * inv);
            }
        }
    }
}

// One launch casting all six f32 weight/activation blobs to bf16.
__global__ __launch_bounds__(256) void cast_all(
    const float* __restrict__ s0, unsigned short* __restrict__ d0,   // x      4194304
    const float* __restrict__ s1, unsigned short* __restrict__ d1,   // q_down 1572864
    const float* __restrict__ s2, unsigned short* __restrict__ d2,   // q_up   2359296
    const float* __restrict__ s3, unsigned short* __restrict__ d3,   // kv_down1179648
    const float* __restrict__ s4, unsigned short* __restrict__ d4,   // kv_up  2097152
    const float* __restrict__ s5, unsigned short* __restrict__ d5)   // out_w  4194304
{
    long i = (long)(blockIdx.x * 256 + threadIdx.x) * 4;
    const float* s; unsigned short* d; long off;
    if      (i <  4194304L){ s = s0; d = d0; off = i; }
    else if (i <  5767168L){ s = s1; d = d1; off = i -  4194304L; }
    else if (i <  8126464L){ s = s2; d = d2; off = i -  5767168L; }
    else if (i <  9306112L){ s = s3; d = d3; off = i -  8126464L; }
    else if (i < 11403264L){ s = s4; d = d4; off = i -  9306112L; }
    else                   { s = s5; d = d5; off = i - 11403264L; }
    float4 v = *(const float4*)(s + off);
    *(ushort4*)(d + off) = make_ushort4(f2b(v.x), f2b(v.y), f2b(v.z), f2b(v.w));
}

// Fused down-proj epilogue. p = [4][2048][1344] bf16 split-K partials.
// Also broadcasts the roped k_rot into khcat cols 128..192 for all 16 heads
// (value already in a register; khcat cols 0..127 are written later by vk3 —
// disjoint bytes, no race). [R13-verified]
__global__ __launch_bounds__(256) void fused_down_post(
    const unsigned short* __restrict__ p,
    const float* __restrict__ q_down_b, const float* __restrict__ kv_down_b,
    const float* __restrict__ q_norm_s, const float* __restrict__ kv_norm_s,
    unsigned short* __restrict__ qn, unsigned short* __restrict__ kcat,
    unsigned short* __restrict__ khcat)       // [32][1024][192]
{
    __shared__ float row[1344];
    __shared__ float red[4];
    const int t = blockIdx.x, tid = threadIdx.x;
    const long S = 2752512L; // 2048*1344
    const unsigned short* b0 = p + (size_t)t * 1344;
    for (int c = tid; c < 1344; c += 256){
        float v = b2f(b0[c]) + b2f(b0[c + S]) + b2f(b0[c + 2*S]) + b2f(b0[c + 3*S]);
        v += (c < 768) ? q_down_b[c] : kv_down_b[c - 768];
        row[c] = v;
    }
    __syncthreads();
    const int lane = tid & 63, w = tid >> 6;
    float ss = 0.f;
    for (int c = tid; c < 768; c += 256){ float v = row[c]; ss += v * v; }
    #pragma unroll
    for (int o = 32; o > 0; o >>= 1) ss += __shfl_xor(ss, o, 64);
    if (lane == 0) red[w] = ss;
    __syncthreads();
    const float inv1 = rsqrtf((red[0]+red[1]+red[2]+red[3]) / 768.f + 1e-6f);
    __syncthreads();
    ss = 0.f;
    for (int c = tid; c < 512; c += 256){ float v = row[768 + c]; ss += v * v; }
    #pragma unroll
    for (int o = 32; o > 0; o >>= 1) ss += __shfl_xor(ss, o, 64);
    if (lane == 0) red[w] = ss;
    __syncthreads();
    const float inv2 = rsqrtf((red[0]+red[1]+red[2]+red[3]) / 512.f + 1e-6f);
    for (int c = tid; c < 768; c += 256)
        qn[(size_t)t * 768 + c] = f2b(q_norm_s[c] * row[c] * inv1);
    for (int c = tid; c < 512; c += 256)
        kcat[(size_t)t * 576 + c] = f2b(kv_norm_s[c] * row[768 + c] * inv2);
    if (tid < 64){
        const int d = tid, s = t & 1023;
        float x  = row[1280 + d];
        float xp = (d < 32) ? -row[1280 + d + 32] : row[1280 + d - 32];
        float ang = (float)s * powf(10000.f, -(float)(2 * (d & 31)) / 64.f);
        const unsigned short kv = f2b(x * cosf(ang) + xp * sinf(ang));
        kcat[(size_t)t * 576 + 512 + d] = kv;
        // broadcast to khcat[b, 0..15][s][128+d]
        const size_t base = ((size_t)((t >> 10) * 16) * 1024 + s) * 192 + 128 + d;
        #pragma unroll
        for (int hh = 0; hh < 16; ++hh)
            khcat[base + (size_t)hh * 196608] = kv;
    }
}

// out = p[0] + p[1] + bias (p bf16 partials, out f32 2048x2048)
__global__ __launch_bounds__(256) void reduce_out(
    const unsigned short* __restrict__ p, const float* __restrict__ bias,
    float* __restrict__ out)
{
    const long S = 4194304L;
    long i = (long)(blockIdx.x * 256 + threadIdx.x) * 4;
    ushort4 a = *(const ushort4*)(p + i);
    ushort4 b = *(const ushort4*)(p + i + S);
    float4 bb = *(const float4*)(bias + (i & 2047));
    float4 r = make_float4(b2f(a.x) + b2f(b.x) + bb.x, b2f(a.y) + b2f(b.y) + bb.y,
                           b2f(a.z) + b2f(b.z) + bb.z, b2f(a.w) + b2f(b.w) + bb.w);
    *(float4*)(out + i) = r;
}

// Pairwise in-place RoPE on qu's q_rot slices (thread owns the (d, d+32)
// pair -> no race). q-only: khcat k_rot broadcast now lives in fdp.
// High-occupancy elementwise kernel — the right home for the trig.
__global__ __launch_bounds__(256) void rope_q(
    unsigned short* __restrict__ qu)          // [2048][3072]
{
    const long idx = (long)blockIdx.x * 256 + threadIdx.x;  // < 1048576
    const int d   = idx & 31;
    const int h   = (idx >> 5) & 15;
    const int tok = (int)(idx >> 9);
    const int s   = tok & 1023;
    unsigned short* base = qu + (size_t)tok * 3072 + h * 192 + 128;
    float x1 = b2f(base[d]), x2 = b2f(base[d + 32]);
    float ang = (float)s * powf(10000.f, -(float)d / 32.f);
    float c = cosf(ang), sn = sinf(ang);
    base[d]      = f2b(x1 * c - x2 * sn);
    base[d + 32] = f2b(x2 * c + x1 * sn);
}

extern "C" void kernel_launch(void* const* d_in, const int* in_sizes, int n_in,
                              void* d_out, int out_size, void* d_ws, size_t ws_size,
                              hipStream_t stream)
{
    const float* x         = (const float*)d_in[0];
    const float* q_down_w  = (const float*)d_in[3];
    const float* q_down_b  = (const float*)d_in[4];
    const float* q_norm_s  = (const float*)d_in[5];
    const float* q_up_w    = (const float*)d_in[6];
    const float* q_up_b    = (const float*)d_in[7];
    const float* kv_down_w = (const float*)d_in[8];
    const float* kv_down_b = (const float*)d_in[9];
    const float* kv_norm_s = (const float*)d_in[10];
    const float* kv_up_w   = (const float*)d_in[11];
    const float* out_w     = (const float*)d_in[12];
    const float* out_b     = (const float*)d_in[13];
    float* out = (float*)d_out;

    // Workspace layout (bytes), peak 100,925,440:
    char* ws = (char*)d_ws;
    unsigned short* kvuw  = (unsigned short*)(ws + 0);           // [4096][512] (w_k rows 0..2047, w_v 2048..4095)
    unsigned short* outw  = (unsigned short*)(ws + 4194304);     // [2048][2048]
    unsigned short* kcat  = (unsigned short*)(ws + 12582912);    // [2048][576]
    unsigned short* vhT   = (unsigned short*)(ws + 14942208);    // [2][16][128][1024]
    unsigned short* khcat = (unsigned short*)(ws + 23330816);    // [32][1024][192]
    unsigned short* ctx   = (unsigned short*)(ws + 35913728);    // [2048][2048] bf16
    unsigned short* qu    = (unsigned short*)(ws + 44302336);    // [2048][3072] (live through flash)
    unsigned short* qn    = (unsigned short*)(ws + 56885248);    // [2048][768]
    unsigned short* p_qkv = (unsigned short*)(ws + 60030976);    // [4][2048][1344] bf16 (dead after fdp)
    unsigned short* p_out = (unsigned short*)(ws + 60030976);    // [2][2048][2048] bf16 (alias p_qkv)
    unsigned short* xb    = (unsigned short*)(ws + 82051072);    // [2048][2048]
    unsigned short* qkdw  = (unsigned short*)(ws + 90439680);    // [1408][2048] concat down-proj w
    unsigned short* quw   = (unsigned short*)(ws + 96206848);    // [3072][768]

    dim3 blk(256);

    // casts: q_down -> qkdw rows 0..767, kv_down -> qkdw rows 768..1343
    cast_all<<<15232, blk, 0, stream>>>(x, xb, q_down_w, qkdw, q_up_w, quw,
                                        kv_down_w, qkdw + 1572864, kv_up_w, kvuw, out_w, outw);

    // k1 (split-K x4, bf16 partials): p_qkv[s] = x[:, s*512:] @ qkdw[:, s*512:]^T
    mfma_gemm_bt<unsigned short><<<dim3(11, 16, 4), blk, 0, stream>>>(
        xb, qkdw, nullptr, p_qkv, 2048, 1344, 512, 2048, 2048, 1344,
        4, 0L, 512L, 0L, 512L, 0L, 2752512L, 1.0f, 0);
    // fused: partial-sum + biases + q-rmsnorm -> qn, kv-rmsnorm/rope -> kcat,
    // + roped k_rot broadcast into khcat cols 128..192
    fused_down_post<<<2048, blk, 0, stream>>>(p_qkv, q_down_b, kv_down_b,
                                              q_norm_s, kv_norm_s, qn, kcat, khcat);
    // merged vhT + kh + k3 (896 blocks: k3 backfills the vk tail)
    mfma_gemm_vk3<<<dim3(896), blk, 0, stream>>>(kvuw, kcat, vhT, khcat,
                                                 qn, quw, q_up_b, qu);
    // rope q (in-place on qu; q-only, 4096 blocks)
    rope_q<<<4096, blk, 0, stream>>>(qu);
    // fused attention v10 (R12-exact): LPT queue + XCD-local z
    flash_attn<<<dim3(512), blk, 0, stream>>>(qu, khcat, vhT, ctx);
    // k11 (split-K x2, bf16 partials, 512 blocks): p_out[s] = ctx[:, s*1024:] @ outw[:, s*1024:]^T
    mfma_gemm_bt<unsigned short><<<dim3(16, 16, 2), blk, 0, stream>>>(
        ctx, outw, nullptr, p_out, 2048, 2048, 1024, 2048, 2048, 2048,
        2, 0L, 1024L, 0L, 1024L, 0L, 4194304L, 1.0f, 0);
    // out = p_out[0] + p_out[1] + out_b
    reduce_out<<<4096, blk, 0, stream>>>(p_out, out_b, out);
}

// Round 15
// 281.900 us; speedup vs baseline: 1.0448x; 1.0086x over previous
//
#include <hip/hip_runtime.h>
#include <stdint.h>
#include <stddef.h>

// DIM=2048, H=16, Q_RANK=768, KV_RANK=512, QK_STATIC=128, QK_ROT=64,
// QK_TOTAL=192, V_DIM=128, BS=2, SEQ=1024, NTOK=2048.
// Score contraction absorbed on the K side: kh[b,h] = kvn @ W_k[h]^T (128-dim),
// so scores = [q_static | q_rot] . [kh | k_rot] over 192 dims (vs 576).

typedef __attribute__((ext_vector_type(8))) short bf16x8;
typedef __attribute__((ext_vector_type(4))) float f32x4;

__device__ inline float b2f(unsigned short v){
    union { unsigned u; float f; } x; x.u = ((unsigned)v) << 16; return x.f;
}
__device__ inline unsigned short f2b(float f){
    union { float f; unsigned u; } x; x.f = f;
    unsigned r = x.u + 0x7fffu + ((x.u >> 16) & 1u);
    return (unsigned short)(r >> 16);
}

// async global->LDS, 16B per lane. LDS dest = wave-uniform base + lane*16.
__device__ __forceinline__ void gl2lds16(const unsigned short* g, unsigned short* l){
    __builtin_amdgcn_global_load_lds(
        (__attribute__((address_space(1))) void*)const_cast<unsigned short*>(g),
        (__attribute__((address_space(3))) void*)l,
        16, 0, 0);
}

// Shared GEMM body: C[M,N](+=bias) = alpha*(A @ B^T), bf16 in, fp32 acc.
// 128x128 tile, BK=32, 4 waves 2x2, 16x16x32 MFMA, 3-deep global_load_lds
// pipeline (vmcnt(4) waits, raw s_barrier, no full drain). LDS bank swizzle:
// stage global chunk (lane&3)^((lane>>3)&3); reads use chunk g^((row>>1)&3).
// causal bit0: -1e9 above diagonal in epilogue.
template<typename TC>
static __device__ __forceinline__ void gemm_body(
    unsigned short (*As)[4096], unsigned short (*Bs)[4096],
    const unsigned short* A, const unsigned short* B,
    const float* bias, TC* C,
    int N, int K, int lda, int ldb, int ldc,
    int m0, int n0, float alpha, int causal)
{
    const int tid = threadIdx.x, w = tid >> 6, lane = tid & 63;
    const int wm = w >> 1, wn = w & 1;

    const int srow = w * 32 + (lane >> 2);
    const int schunk = ((lane & 3) ^ ((lane >> 3) & 3)) * 8;   // row-bit-1/2 swizzle
    const unsigned short* gA = A + (size_t)(m0 + srow) * lda + schunk;
    const unsigned short* gB = B + (size_t)(n0 + srow) * ldb + schunk;

    const int ktiles = K >> 5;
    auto stage = [&](int buf, int kt){
        const int k0 = kt << 5;
        gl2lds16(gA + k0,            &As[buf][w * 1024]);
        gl2lds16(gA + k0 + 16 * lda, &As[buf][w * 1024 + 512]);
        gl2lds16(gB + k0,            &Bs[buf][w * 1024]);
        gl2lds16(gB + k0 + 16 * ldb, &Bs[buf][w * 1024 + 512]);
    };
    stage(0, 0);
    if (ktiles > 1) stage(1, 1);

    f32x4 acc[4][4] = {};
    const int lm = lane & 15;
    const int kq = (((lane >> 4) ^ (lm >> 1)) & 3) * 8;        // matches stage swizzle

    int cur = 0;
    for (int kt = 0; kt < ktiles; ++kt){
        if (kt + 1 < ktiles) __builtin_amdgcn_s_waitcnt(0xF74);
        else                 __builtin_amdgcn_s_waitcnt(0xF70);
        __builtin_amdgcn_s_barrier();
        __asm__ volatile("" ::: "memory");
        if (kt + 2 < ktiles) stage(cur >= 1 ? cur - 1 : 2, kt + 2);
        bf16x8 af[4], bfr[4];
        #pragma unroll
        for (int i = 0; i < 4; ++i)
            af[i] = *(const bf16x8*)&As[cur][(wm * 64 + i * 16 + lm) * 32 + kq];
        #pragma unroll
        for (int j = 0; j < 4; ++j)
            bfr[j] = *(const bf16x8*)&Bs[cur][(wn * 64 + j * 16 + lm) * 32 + kq];
        #pragma unroll
        for (int i = 0; i < 4; ++i)
            #pragma unroll
            for (int j = 0; j < 4; ++j)
                acc[i][j] = __builtin_amdgcn_mfma_f32_16x16x32_bf16(af[i], bfr[j], acc[i][j], 0, 0, 0);
        __asm__ volatile("" ::: "memory");
        cur = (cur == 2) ? 0 : cur + 1;
    }

    // C/D layout: col = lane&15, row = (lane>>4)*4 + reg
    #pragma unroll
    for (int i = 0; i < 4; ++i){
        const int m = m0 + wm * 64 + i * 16 + (lane >> 4) * 4;
        #pragma unroll
        for (int j = 0; j < 4; ++j){
            const int n = n0 + wn * 64 + j * 16 + lm;
            if (n < N){
                const float bb = bias ? bias[n] : 0.f;
                #pragma unroll
                for (int r = 0; r < 4; ++r){
                    float v = acc[i][j][r] * alpha + bb;
                    if ((causal & 1) && n > m + r) v = -1e9f;
                    if constexpr (sizeof(TC) == 2)
                        C[(size_t)(m + r) * ldc + n] = (TC)f2b(v);
                    else
                        C[(size_t)(m + r) * ldc + n] = (TC)v;
                }
            }
        }
    }
}

// Generic launcher (R6-exact).
// causal bit0: compact triangular tile decode (index = bm), mask in epilogue.
// causal bit1: K = min(K, m0+128).  causal bit2: z-first grid.
template<typename TC>
__global__ __launch_bounds__(256) void mfma_gemm_bt(
    const unsigned short* __restrict__ A, const unsigned short* __restrict__ B,
    const float* __restrict__ bias, TC* __restrict__ C,
    int M, int N, int K, int lda, int ldb, int ldc,
    int zdiv, long sA_hi, long sA_lo, long sB_hi, long sB_lo, long sC_hi, long sC_lo,
    float alpha, int causal)
{
    int z, bm, bn;
    if (causal & 4){ z = blockIdx.x; bm = blockIdx.y; bn = blockIdx.z; }
    else           { z = blockIdx.z; bm = blockIdx.y; bn = blockIdx.x; }
    int m0, n0;
    if (causal & 1){
        int i = bm;
        int mt = (int)((sqrtf(8.f * i + 1.f) - 1.f) * 0.5f);
        while ((mt + 1) * (mt + 2) / 2 <= i) ++mt;
        while (mt * (mt + 1) / 2 > i) --mt;
        n0 = (i - mt * (mt + 1) / 2) * 128;
        m0 = mt * 128;
    } else { m0 = bm * 128; n0 = bn * 128; }
    if (causal & 2) K = min(K, m0 + 128);

    __shared__ unsigned short As[3][4096];
    __shared__ unsigned short Bs[3][4096];
    const int zh = z / zdiv, zl = z % zdiv;
    A += (size_t)zh * sA_hi + (size_t)zl * sA_lo;
    B += (size_t)zh * sB_hi + (size_t)zl * sB_lo;
    C += (size_t)zh * sC_hi + (size_t)zl * sC_lo;

    gemm_body<TC>(As, Bs, A, B, bias, C, N, K, lda, ldb, ldc, m0, n0, alpha, causal);
}

// Merged k1 + deferred casts (9152 blocks, 1-D).
// id < 704 (k1, EXACT old dispatch order for dim3(11,16,4): x fastest):
//   bn=id%11, bm=(id/11)%16, zl=id/176.
//   p_qkv[zl] = x[:, zl*512:] @ qkdw[:, zl*512:]^T  (split-K x4 partials)
// id >= 704: cast blocks for {q_up->quw, kv_up->kvuw, out_w->outw} — these
//   outputs are first read by vk3/k11 (later launches), so they can backfill
//   k1's latency-bound grid (same mechanism as the vk3 merge; k1 runs at
//   ~1TB/s with ~5TB/s headroom, the 52MB of cast traffic hides under it).
__global__ __launch_bounds__(256) void mfma_k1_cast(
    const unsigned short* __restrict__ xb, const unsigned short* __restrict__ qkdw,
    unsigned short* __restrict__ p_qkv,
    const float* __restrict__ s_qup,  unsigned short* __restrict__ d_quw,   // 2359296
    const float* __restrict__ s_kvup, unsigned short* __restrict__ d_kvuw,  // 2097152
    const float* __restrict__ s_outw, unsigned short* __restrict__ d_outw)  // 4194304
{
    __shared__ unsigned short As[3][4096];
    __shared__ unsigned short Bs[3][4096];
    const int id = blockIdx.x;
    if (id < 704){
        const int bn = id % 11, rem = id / 11;
        const int bm = rem % 16, zl = rem / 16;
        gemm_body<unsigned short>(As, Bs,
            xb + (size_t)zl * 512, qkdw + (size_t)zl * 512, nullptr,
            p_qkv + (size_t)zl * 2752512,
            1344, 512, 2048, 2048, 1344, bm * 128, bn * 128, 1.0f, 0);
    } else {
        long i = ((long)(id - 704) * 256 + threadIdx.x) * 4;   // < 8650752
        const float* s; unsigned short* d; long off;
        if      (i < 2359296L){ s = s_qup;  d = d_quw;  off = i; }
        else if (i < 4456448L){ s = s_kvup; d = d_kvuw; off = i - 2359296L; }
        else                  { s = s_outw; d = d_outw; off = i - 4456448L; }
        float4 v = *(const float4*)(s + off);
        *(ushort4*)(d + off) = make_ushort4(f2b(v.x), f2b(v.y), f2b(v.z), f2b(v.w));
    }
}

// Merged vhT + kh + k3 launch (896 blocks, 1-D). All three GEMMs depend only
// on fdp outputs (kcat, qn) + weights cast by mfma_k1_cast; k3 blocks
// backfill the vk tail.
// id < 512  (vk part): p=x&1, z=x>>1 (x=id&63, y=id>>6).
// id >= 512 (k3 part): bn=lid%24 fastest, bm=lid/24.
__global__ __launch_bounds__(256) void mfma_gemm_vk3(
    const unsigned short* __restrict__ kvuw,  // [4096][512]: w_k rows 0..2047, w_v 2048..4095
    const unsigned short* __restrict__ kcat,  // [2048][576] (kvn rows, ldb=576)
    unsigned short* __restrict__ vhT,         // [2][16][128][1024]
    unsigned short* __restrict__ khcat,       // [32][1024][192]
    const unsigned short* __restrict__ qn,    // [2048][768]
    const unsigned short* __restrict__ quw,   // [3072][768]
    const float* __restrict__ q_up_b,
    unsigned short* __restrict__ qu)          // [2048][3072]
{
    __shared__ unsigned short As[3][4096];
    __shared__ unsigned short Bs[3][4096];
    const int id = blockIdx.x;
    if (id < 512){
        const int x = id & 63, y = id >> 6;
        const int p = x & 1, z = x >> 1;
        const int b = z >> 4, h = z & 15;
        if (p == 0){
            const unsigned short* A = kvuw + 1048576 + (size_t)h * 65536;  // w_v[h]
            const unsigned short* B = kcat + (size_t)b * 589824;
            unsigned short* C = vhT + (size_t)b * 2097152 + (size_t)h * 131072;
            gemm_body<unsigned short>(As, Bs, A, B, nullptr, C,
                                      1024, 512, 512, 576, 1024, 0, y * 128, 1.0f, 0);
        } else {
            const unsigned short* A = kcat + (size_t)b * 589824;
            const unsigned short* B = kvuw + (size_t)h * 65536;            // w_k[h]
            unsigned short* C = khcat + (size_t)b * 3145728 + (size_t)h * 196608;
            gemm_body<unsigned short>(As, Bs, A, B, nullptr, C,
                                      128, 512, 576, 512, 192, y * 128, 0, 1.0f, 0);
        }
    } else {
        const int lid = id - 512;             // 0..383
        const int bn = lid % 24, bm = lid / 24;
        gemm_body<unsigned short>(As, Bs, qn, quw, q_up_b, qu,
                                  3072, 768, 768, 768, 3072,
                                  bm * 128, bn * 128, 1.0f, 0);
    }
}

// Fused causal attention v10 (R12-exact; measured best 41.4us): v6 body +
// LPT (longest-first) global queue with XCD-local z.
// Makespan-limited under ~1 block/CU with greedy in-order backfill. LPT: 8
// classes of 64 blocks, class c has nkt=8-c (descending); greedy backfill
// pairs every CU to ~9 iters. Within a class, z=(idx&7)+8*((idx>>3)&3)
// keeps z%8==t%8 -> same-XCD K/V. Chunk0 cross-tile prefetch (Ks[2]);
// counted vmcnt (24/20/16); lgkm-only barriers; V drained at PV; setprio.
__global__ __launch_bounds__(256) void flash_attn(
    const unsigned short* __restrict__ qu,    // [2048][3072], q_rot slices roped
    const unsigned short* __restrict__ khcat, // [32][1024][192] = [kh | k_rot]
    const unsigned short* __restrict__ vhT,   // [2][16][128][1024]
    unsigned short* __restrict__ ctx)         // [2048][2048]
{
    const int t = blockIdx.x;
    const int cls = t >> 6;                   // 0..7, nkt = 8-cls (LPT order)
    const int idx = t & 63;
    const int z = (idx & 7) + 8 * ((idx >> 3) & 3);  // z%8 == t%8 -> XCD-local
    const int mt = 2 * (7 - cls) + (idx >> 5);
    const int b = z >> 4, h = z & 15;
    const int m0 = mt * 64;
    const int nkt = (mt >> 1) + 1;            // == 8-cls

    __shared__ char smem[74240];
    unsigned short (*Qs)[4096] = (unsigned short (*)[4096])smem;            // 3 x 64x64 (Q resident)
    unsigned short (*Ks)[8192] = (unsigned short (*)[8192])(smem + 24576);  // 3 x 128x64
    unsigned short* Ps = (unsigned short*)(smem + 24576);                   // 64x136, aliases Ks[0..1]
    float* lrow = (float*)(smem + 73728);                                   // [2][64]

    const unsigned short* kB = khcat + (size_t)z * 196608;
    const unsigned short* vB = vhT + (size_t)z * 131072;

    const int tid = threadIdx.x, w = tid >> 6, lane = tid & 63;
    const int wm = w >> 1, wn = w & 1;
    const int lm = lane & 15, g = lane >> 4;
    const int kq = g * 8;
    const int rs7 = lm & 7;                   // row&7 for swizzled reads

    if (tid < 128) lrow[tid] = 0.f;

    const int srow8 = lane >> 3;              // 0..7
    const int soff8 = ((lane & 7) ^ (lane >> 3)) * 8;  // swizzled global chunk
    const unsigned short* gQ = qu + (size_t)(b * 1024 + m0 + w * 16 + srow8) * 3072
                               + h * 192 + soff8;

    // Q resident: 192 k = 3 chunk-buffers, staged once (6 loads/wave).
    #pragma unroll
    for (int c = 0; c < 3; ++c){
        gl2lds16(gQ + c * 64,            &Qs[c][w * 1024]);
        gl2lds16(gQ + c * 64 + 8 * 3072, &Qs[c][w * 1024 + 512]);
    }

    // K chunks with FIXED buffer roles: chunk0 -> Ks[2] (prefetched one
    // kv-tile ahead), chunk1 -> Ks[0], chunk2 -> Ks[1].
    auto stageK = [&](int buf, int kt, int c){
        const unsigned short* gK = kB + (size_t)(kt * 128 + w * 32 + srow8) * 192
                                   + c * 64 + soff8;
        gl2lds16(gK,            &Ks[buf][w * 2048]);
        gl2lds16(gK + 8 * 192,  &Ks[buf][w * 2048 + 512]);
        gl2lds16(gK + 16 * 192, &Ks[buf][w * 2048 + 1024]);
        gl2lds16(gK + 24 * 192, &Ks[buf][w * 2048 + 1536]);
    };
    stageK(2, 0, 0);                          // chunk0 of tile 0

    f32x4 Oacc[2][4] = {};
    const float scl = 0.07216878364870322f;   // 1/sqrt(192)

    for (int kt = 0; kt < nkt; ++kt){
        stageK(0, kt, 1);                     // chunk1 -> buf0 (Ps dead now)
        stageK(1, kt, 2);                     // chunk2 -> buf1
        __asm__ volatile("" ::: "memory");    // pin V loads AFTER K stages
        bf16x8 vfr[4][4];
        #pragma unroll
        for (int j = 0; j < 4; ++j)
            #pragma unroll
            for (int kc = 0; kc < 4; ++kc)
                vfr[j][kc] = *(const bf16x8*)(vB + (size_t)(wn * 64 + j * 16 + lm) * 1024
                                              + kt * 128 + kc * 32 + kq);
        __asm__ volatile("" ::: "memory");

        // vm queue (oldest first), steady state: [pf chunk0(4)] (kt=0: Q(6)+
        // chunk0(4)), chunk1(4), chunk2(4), V(16) = 28 (34 on kt=0).
        f32x4 S[2][4] = {};
        #pragma unroll
        for (int c = 0; c < 3; ++c){
            if      (c == 0) __builtin_amdgcn_s_waitcnt(0x4F78);  // vmcnt(24): chunk0 (+Q) in
            else if (c == 1) __builtin_amdgcn_s_waitcnt(0x4F74);  // vmcnt(20): chunk1 in
            else             __builtin_amdgcn_s_waitcnt(0x4F70);  // vmcnt(16): chunk2 in, V in flight
            __builtin_amdgcn_s_barrier();
            __asm__ volatile("" ::: "memory");
            const int bufc = (c == 0) ? 2 : (c - 1);
            bf16x8 af[2][2], bfr[4][2];
            #pragma unroll
            for (int i = 0; i < 2; ++i)
                #pragma unroll
                for (int kk = 0; kk < 2; ++kk)
                    af[i][kk] = *(const bf16x8*)&Qs[c][(wm * 32 + i * 16 + lm) * 64
                                                       + (((kk * 4 + g) ^ rs7) * 8)];
            #pragma unroll
            for (int j = 0; j < 4; ++j)
                #pragma unroll
                for (int kk = 0; kk < 2; ++kk)
                    bfr[j][kk] = *(const bf16x8*)&Ks[bufc][(wn * 64 + j * 16 + lm) * 64
                                                           + (((kk * 4 + g) ^ rs7) * 8)];
            __builtin_amdgcn_s_setprio(1);
            #pragma unroll
            for (int kk = 0; kk < 2; ++kk)
                #pragma unroll
                for (int i = 0; i < 2; ++i)
                    #pragma unroll
                    for (int j = 0; j < 4; ++j)
                        S[i][j] = __builtin_amdgcn_mfma_f32_16x16x32_bf16(af[i][kk], bfr[j][kk], S[i][j], 0, 0, 0);
            __builtin_amdgcn_s_setprio(0);
            __asm__ volatile("" ::: "memory");
        }
        // all QK reads of Ks done -> Ps (alias) writable. lgkm-only barrier:
        // keep the vm queue (V + upcoming prefetch) alive across it.
        __builtin_amdgcn_s_waitcnt(0xC07F);   // lgkmcnt(0), vmcnt untouched
        __builtin_amdgcn_s_barrier();
        __asm__ volatile("" ::: "memory");
        if (kt + 1 < nkt) stageK(2, kt + 1, 0);   // prefetch next chunk0 -> buf2

        // softmax numerator (global-index causal mask on the diagonal tile);
        // row sums; P -> LDS (aliased on Ks[0..1]) in [m][k] layout.
        const bool diag = (kt == (mt >> 1));
        #pragma unroll
        for (int i = 0; i < 2; ++i){
            float rs[4] = {0.f, 0.f, 0.f, 0.f};
            #pragma unroll
            for (int j = 0; j < 4; ++j){
                const int nloc = wn * 64 + j * 16 + lm;
                #pragma unroll
                for (int r2 = 0; r2 < 4; ++r2){
                    const int mloc = wm * 32 + i * 16 + g * 4 + r2;
                    float p = __expf(S[i][j][r2] * scl);
                    if (diag && (kt * 128 + nloc) > (m0 + mloc)) p = 0.f;
                    rs[r2] += p;
                    Ps[mloc * 136 + nloc] = f2b(p);
                }
            }
            #pragma unroll
            for (int r2 = 0; r2 < 4; ++r2){
                rs[r2] += __shfl_xor(rs[r2], 1, 64);
                rs[r2] += __shfl_xor(rs[r2], 2, 64);
                rs[r2] += __shfl_xor(rs[r2], 4, 64);
                rs[r2] += __shfl_xor(rs[r2], 8, 64);
            }
            if (lm == 0){
                #pragma unroll
                for (int r2 = 0; r2 < 4; ++r2)
                    lrow[wn * 64 + wm * 32 + i * 16 + g * 4 + r2] += rs[r2];
            }
        }
        __asm__ volatile("" ::: "memory");
        __builtin_amdgcn_s_waitcnt(0xC07F);   // Ps + lrow visible
        __builtin_amdgcn_s_barrier();
        __asm__ volatile("" ::: "memory");

        // O += P @ V^T  (A = Ps rows, B = vfr registers). V drained here
        // (in-order vm retirement; prefetched chunk0 may stay in flight).
        if (kt + 1 < nkt) __builtin_amdgcn_s_waitcnt(0xF74);  // vmcnt(4)
        else              __builtin_amdgcn_s_waitcnt(0xF70);  // vmcnt(0)
        #pragma unroll
        for (int kc = 0; kc < 4; ++kc){
            bf16x8 pa[2];
            #pragma unroll
            for (int i = 0; i < 2; ++i)
                pa[i] = *(const bf16x8*)&Ps[(wm * 32 + i * 16 + lm) * 136 + kc * 32 + kq];
            __builtin_amdgcn_s_setprio(1);
            #pragma unroll
            for (int i = 0; i < 2; ++i)
                #pragma unroll
                for (int j = 0; j < 4; ++j)
                    Oacc[i][j] = __builtin_amdgcn_mfma_f32_16x16x32_bf16(pa[i], vfr[j][kc], Oacc[i][j], 0, 0, 0);
            __builtin_amdgcn_s_setprio(0);
        }
        __asm__ volatile("" ::: "memory");
        __builtin_amdgcn_s_waitcnt(0xC07F);   // Ps reads done -> next kt restages buf0/1
        __builtin_amdgcn_s_barrier();
        __asm__ volatile("" ::: "memory");
    }

    // normalize and store: ctx[(b*1024+m0+row)][h*128 + col]
    unsigned short* cBase = ctx + ((size_t)(b * 1024 + m0)) * 2048 + h * 128;
    #pragma unroll
    for (int i = 0; i < 2; ++i){
        #pragma unroll
        for (int r2 = 0; r2 < 4; ++r2){
            const int row = wm * 32 + i * 16 + g * 4 + r2;
            const float inv = 1.f / (lrow[row] + lrow[64 + row]);
            #pragma unroll
            for (int j = 0; j < 4; ++j){
                const int col = wn * 64 + j * 16 + lm;
                cBase[(size_t)row * 2048 + col] = f2b(Oacc[i][j][r2] * inv);
            }
        }
    }
}

// Pre-cast: only the blobs k1 needs (x -> xb, q_down/kv_down -> qkdw).
// x 4194304 | q_down 1572864 | kv_down 1179648 = 6946816 elems, 6784 blocks.
__global__ __launch_bounds__(256) void cast_pre(
    const float* __restrict__ s0, unsigned short* __restrict__ d0,   // x
    const float* __restrict__ s1, unsigned short* __restrict__ d1,   // q_down
    const float* __restrict__ s2, unsigned short* __restrict__ d2)   // kv_down
{
    long i = (long)(blockIdx.x * 256 + threadIdx.x) * 4;
    const float* s; unsigned short* d; long off;
    if      (i < 4194304L){ s = s0; d = d0; off = i; }
    else if (i < 5767168L){ s = s1; d = d1; off = i - 4194304L; }
    else                  { s = s2; d = d2; off = i - 5767168L; }
    float4 v = *(const float4*)(s + off);
    *(ushort4*)(d + off) = make_ushort4(f2b(v.x), f2b(v.y), f2b(v.z), f2b(v.w));
}

// Fused down-proj epilogue. p = [4][2048][1344] bf16 split-K partials.
// Also broadcasts the roped k_rot into khcat cols 128..192 for all 16 heads
// (khcat cols 0..127 written later by vk3 — disjoint bytes). [R13-verified]
__global__ __launch_bounds__(256) void fused_down_post(
    const unsigned short* __restrict__ p,
    const float* __restrict__ q_down_b, const float* __restrict__ kv_down_b,
    const float* __restrict__ q_norm_s, const float* __restrict__ kv_norm_s,
    unsigned short* __restrict__ qn, unsigned short* __restrict__ kcat,
    unsigned short* __restrict__ khcat)       // [32][1024][192]
{
    __shared__ float row[1344];
    __shared__ float red[4];
    const int t = blockIdx.x, tid = threadIdx.x;
    const long S = 2752512L; // 2048*1344
    const unsigned short* b0 = p + (size_t)t * 1344;
    for (int c = tid; c < 1344; c += 256){
        float v = b2f(b0[c]) + b2f(b0[c + S]) + b2f(b0[c + 2*S]) + b2f(b0[c + 3*S]);
        v += (c < 768) ? q_down_b[c] : kv_down_b[c - 768];
        row[c] = v;
    }
    __syncthreads();
    const int lane = tid & 63, w = tid >> 6;
    float ss = 0.f;
    for (int c = tid; c < 768; c += 256){ float v = row[c]; ss += v * v; }
    #pragma unroll
    for (int o = 32; o > 0; o >>= 1) ss += __shfl_xor(ss, o, 64);
    if (lane == 0) red[w] = ss;
    __syncthreads();
    const float inv1 = rsqrtf((red[0]+red[1]+red[2]+red[3]) / 768.f + 1e-6f);
    __syncthreads();
    ss = 0.f;
    for (int c = tid; c < 512; c += 256){ float v = row[768 + c]; ss += v * v; }
    #pragma unroll
    for (int o = 32; o > 0; o >>= 1) ss += __shfl_xor(ss, o, 64);
    if (lane == 0) red[w] = ss;
    __syncthreads();
    const float inv2 = rsqrtf((red[0]+red[1]+red[2]+red[3]) / 512.f + 1e-6f);
    for (int c = tid; c < 768; c += 256)
        qn[(size_t)t * 768 + c] = f2b(q_norm_s[c] * row[c] * inv1);
    for (int c = tid; c < 512; c += 256)
        kcat[(size_t)t * 576 + c] = f2b(kv_norm_s[c] * row[768 + c] * inv2);
    if (tid < 64){
        const int d = tid, s = t & 1023;
        float x  = row[1280 + d];
        float xp = (d < 32) ? -row[1280 + d + 32] : row[1280 + d - 32];
        float ang = (float)s * powf(10000.f, -(float)(2 * (d & 31)) / 64.f);
        const unsigned short kv = f2b(x * cosf(ang) + xp * sinf(ang));
        kcat[(size_t)t * 576 + 512 + d] = kv;
        // broadcast to khcat[b, 0..15][s][128+d]
        const size_t base = ((size_t)((t >> 10) * 16) * 1024 + s) * 192 + 128 + d;
        #pragma unroll
        for (int hh = 0; hh < 16; ++hh)
            khcat[base + (size_t)hh * 196608] = kv;
    }
}

// out = p[0] + p[1] + bias (p bf16 partials, out f32 2048x2048)
__global__ __launch_bounds__(256) void reduce_out(
    const unsigned short* __restrict__ p, const float* __restrict__ bias,
    float* __restrict__ out)
{
    const long S = 4194304L;
    long i = (long)(blockIdx.x * 256 + threadIdx.x) * 4;
    ushort4 a = *(const ushort4*)(p + i);
    ushort4 b = *(const ushort4*)(p + i + S);
    float4 bb = *(const float4*)(bias + (i & 2047));
    float4 r = make_float4(b2f(a.x) + b2f(b.x) + bb.x, b2f(a.y) + b2f(b.y) + bb.y,
                           b2f(a.z) + b2f(b.z) + bb.z, b2f(a.w) + b2f(b.w) + bb.w);
    *(float4*)(out + i) = r;
}

// Pairwise in-place RoPE on qu's q_rot slices (thread owns the (d, d+32)
// pair -> no race). q-only; high-occupancy elementwise home for the trig.
__global__ __launch_bounds__(256) void rope_q(
    unsigned short* __restrict__ qu)          // [2048][3072]
{
    const long idx = (long)blockIdx.x * 256 + threadIdx.x;  // < 1048576
    const int d   = idx & 31;
    const int h   = (idx >> 5) & 15;
    const int tok = (int)(idx >> 9);
    const int s   = tok & 1023;
    unsigned short* base = qu + (size_t)tok * 3072 + h * 192 + 128;
    float x1 = b2f(base[d]), x2 = b2f(base[d + 32]);
    float ang = (float)s * powf(10000.f, -(float)d / 32.f);
    float c = cosf(ang), sn = sinf(ang);
    base[d]      = f2b(x1 * c - x2 * sn);
    base[d + 32] = f2b(x2 * c + x1 * sn);
}

extern "C" void kernel_launch(void* const* d_in, const int* in_sizes, int n_in,
                              void* d_out, int out_size, void* d_ws, size_t ws_size,
                              hipStream_t stream)
{
    const float* x         = (const float*)d_in[0];
    const float* q_down_w  = (const float*)d_in[3];
    const float* q_down_b  = (const float*)d_in[4];
    const float* q_norm_s  = (const float*)d_in[5];
    const float* q_up_w    = (const float*)d_in[6];
    const float* q_up_b    = (const float*)d_in[7];
    const float* kv_down_w = (const float*)d_in[8];
    const float* kv_down_b = (const float*)d_in[9];
    const float* kv_norm_s = (const float*)d_in[10];
    const float* kv_up_w   = (const float*)d_in[11];
    const float* out_w     = (const float*)d_in[12];
    const float* out_b     = (const float*)d_in[13];
    float* out = (float*)d_out;

    // Workspace layout (bytes), peak 100,925,440:
    char* ws = (char*)d_ws;
    unsigned short* kvuw  = (unsigned short*)(ws + 0);           // [4096][512] (w_k rows 0..2047, w_v 2048..4095)
    unsigned short* outw  = (unsigned short*)(ws + 4194304);     // [2048][2048]
    unsigned short* kcat  = (unsigned short*)(ws + 12582912);    // [2048][576]
    unsigned short* vhT   = (unsigned short*)(ws + 14942208);    // [2][16][128][1024]
    unsigned short* khcat = (unsigned short*)(ws + 23330816);    // [32][1024][192]
    unsigned short* ctx   = (unsigned short*)(ws + 35913728);    // [2048][2048] bf16
    unsigned short* qu    = (unsigned short*)(ws + 44302336);    // [2048][3072] (live through flash)
    unsigned short* qn    = (unsigned short*)(ws + 56885248);    // [2048][768]
    unsigned short* p_qkv = (unsigned short*)(ws + 60030976);    // [4][2048][1344] bf16 (dead after fdp)
    unsigned short* p_out = (unsigned short*)(ws + 60030976);    // [2][2048][2048] bf16 (alias p_qkv)
    unsigned short* xb    = (unsigned short*)(ws + 82051072);    // [2048][2048]
    unsigned short* qkdw  = (unsigned short*)(ws + 90439680);    // [1408][2048] concat down-proj w
    unsigned short* quw   = (unsigned short*)(ws + 96206848);    // [3072][768]

    dim3 blk(256);

    // pre-cast: only k1's inputs (x -> xb, q_down/kv_down -> qkdw)
    cast_pre<<<6784, blk, 0, stream>>>(x, xb, q_down_w, qkdw,
                                       kv_down_w, qkdw + 1572864);
    // k1 (split-K x4, 704 blocks) + deferred casts (q_up/kv_up/out_w, 8448
    // blocks backfill)
    mfma_k1_cast<<<dim3(9152), blk, 0, stream>>>(
        xb, qkdw, p_qkv, q_up_w, quw, kv_up_w, kvuw, out_w, outw);
    // fused: partial-sum + biases + q-rmsnorm -> qn, kv-rmsnorm/rope -> kcat,
    // + roped k_rot broadcast into khcat cols 128..192
    fused_down_post<<<2048, blk, 0, stream>>>(p_qkv, q_down_b, kv_down_b,
                                              q_norm_s, kv_norm_s, qn, kcat, khcat);
    // merged vhT + kh + k3 (896 blocks: k3 backfills the vk tail)
    mfma_gemm_vk3<<<dim3(896), blk, 0, stream>>>(kvuw, kcat, vhT, khcat,
                                                 qn, quw, q_up_b, qu);
    // rope q (in-place on qu; q-only, 4096 blocks)
    rope_q<<<4096, blk, 0, stream>>>(qu);
    // fused attention v10 (R12-exact): LPT queue + XCD-local z
    flash_attn<<<dim3(512), blk, 0, stream>>>(qu, khcat, vhT, ctx);
    // k11 (split-K x2, bf16 partials, 512 blocks): p_out[s] = ctx[:, s*1024:] @ outw[:, s*1024:]^T
    mfma_gemm_bt<unsigned short><<<dim3(16, 16, 2), blk, 0, stream>>>(
        ctx, outw, nullptr, p_out, 2048, 2048, 1024, 2048, 2048, 2048,
        2, 0L, 1024L, 0L, 1024L, 0L, 4194304L, 1.0f, 0);
    // out = p_out[0] + p_out[1] + out_b
    reduce_out<<<4096, blk, 0, stream>>>(p_out, out_b, out);
}